// Round 9
// baseline (181.037 us; speedup 1.0000x reference)
//
#include <hip/hip_runtime.h>
#include <cstdint>
#include <cstddef>

#define NI   256
#define QKC  32
#define BS   4
#define NPIX 4096   // 64*64

typedef __bf16 bf16x8 __attribute__((ext_vector_type(8)));
typedef __bf16 bf16x4 __attribute__((ext_vector_type(4)));
typedef float  f32x16 __attribute__((ext_vector_type(16)));

__device__ inline f32x16 zero16() {
    f32x16 z;
    #pragma unroll
    for (int i = 0; i < 16; ++i) z[i] = 0.f;
    return z;
}

// ---------------- Kernel 0: W fp32 -> bf16, concat [320][256] ----------------
__global__ __launch_bounds__(256) void wconv(
    const float* __restrict__ wq, const float* __restrict__ wk,
    const float* __restrict__ wv, __bf16* __restrict__ wbf)
{
    int f = (blockIdx.x * 256 + threadIdx.x) * 4;
    int row = f >> 8, c = f & 255;
    const float* src = row < 32 ? wq + row * NI + c
                     : row < 64 ? wk + (row - 32) * NI + c
                                : wv + (row - 64) * NI + c;
    float4 v = *(const float4*)src;
    __align__(8) __bf16 o4[4] = {(__bf16)v.x, (__bf16)v.y, (__bf16)v.z, (__bf16)v.w};
    *(uint2*)(wbf + f) = *(const uint2*)o4;
}

// ---------------- Kernel 1: QKV projection, single-stage, W direct from L2 ----------------
// One block = 32 pixels x all 320 och. ONE barrier pair. 16-step K loop;
// W fragments read directly from global (L2-resident, 16B contiguous).
// q: (val)*log2e hi/lo split [b][n][32]; k: hi only [b][n][32]; v: bf16 [b][c][n].
// grid (128 n-tiles of 32, 4 b) = 512 blocks, 256 thr.
__global__ __launch_bounds__(256) void qkv_mfma(
    const float* __restrict__ x, const __bf16* __restrict__ wbf,
    const float* __restrict__ bq, const float* __restrict__ bk,
    const float* __restrict__ bv,
    __bf16* __restrict__ qth, __bf16* __restrict__ qtl,
    __bf16* __restrict__ kth, __bf16* __restrict__ vb)
{
    __shared__ __align__(16) __bf16 xT[32][264];   // 16.9 KB; stride 132 dw == 4 mod 32
    __shared__ float bls[320];

    const int t = threadIdx.x, w = t >> 6, lane = t & 63;
    const int l31 = lane & 31, h = lane >> 5;
    const int b = blockIdx.y, n0 = blockIdx.x * 32;

    for (int i = t; i < 320; i += 256)
        bls[i] = i < 32 ? bq[i] : i < 64 ? bk[i - 32] : bv[i - 64];

    {   // stage x transposed: thread covers rows n4..n4+3, channels cb..cb+7
        int n4 = (t & 7) * 4, cb = (t >> 3) * 8;
        float4 xv[8];
        #pragma unroll
        for (int j = 0; j < 8; ++j)
            xv[j] = *(const float4*)(x + ((size_t)(b * NI) + cb + j) * NPIX + n0 + n4);
        #pragma unroll
        for (int i = 0; i < 4; ++i) {
            __align__(16) __bf16 r8[8];
            #pragma unroll
            for (int j = 0; j < 8; ++j) r8[j] = (__bf16)((&xv[j].x)[i]);
            *(uint4*)&xT[n4 + i][cb] = *(const uint4*)r8;
        }
    }
    __syncthreads();

    // wave w owns och tiles otl = w, w+4, w+8 (<10)
    f32x16 acc[3] = {zero16(), zero16(), zero16()};

    #pragma unroll 4
    for (int kk = 0; kk < 16; ++kk) {
        bf16x8 xf = *(const bf16x8*)&xT[l31][kk * 16 + 8 * h];
        #pragma unroll
        for (int jj = 0; jj < 3; ++jj) {
            int otl = w + 4 * jj;
            if (otl < 10) {
                bf16x8 wf = *(const bf16x8*)(wbf + (size_t)(otl * 32 + l31) * NI + kk * 16 + 8 * h);
                if (otl < 2)   // q/k: C[n][och]
                    acc[jj] = __builtin_amdgcn_mfma_f32_32x32x16_bf16(xf, wf, acc[jj], 0, 0, 0);
                else           // v: C[och][n]
                    acc[jj] = __builtin_amdgcn_mfma_f32_32x32x16_bf16(wf, xf, acc[jj], 0, 0, 0);
            }
        }
    }

    #pragma unroll
    for (int jj = 0; jj < 3; ++jj) {
        int otl = w + 4 * jj;
        if (otl >= 10) continue;
        const f32x16& A = acc[jj];
        if (otl < 2) {                         // q (scaled, hi+lo) or k (hi), [b][n][32]
            __bf16* dh = otl == 0 ? qth : kth;
            float bias = bls[otl * 32 + l31];
            float scale = otl == 0 ? 1.4426950408889634f : 1.0f;
            #pragma unroll
            for (int r = 0; r < 16; ++r) {
                int rit = (r & 3) + 8 * (r >> 2) + 4 * h;
                float val = (A[r] + bias) * scale;
                __bf16 hh = (__bf16)val;
                size_t idx = ((size_t)b * NPIX + n0 + rit) * QKC + l31;
                dh[idx] = hh;
                if (otl == 0) qtl[idx] = (__bf16)(val - (float)hh);
            }
        } else {                               // v -> bf16 [b][c][n]
            #pragma unroll
            for (int r = 0; r < 16; ++r) {
                int rit = (r & 3) + 8 * (r >> 2) + 4 * h;
                int c = otl * 32 + rit - 64;
                float val = A[r] + bls[otl * 32 + rit];
                vb[((size_t)(b * NI) + c) * NPIX + n0 + l31] = (__bf16)val;
            }
        }
    }
}

// ---------------- Kernel 2: attention, double-buffered P, ONE barrier/iter ----------------
// grid (64 n-tiles, 2 k-halves, 4 b) = 512 blocks of 256 thr.
// K/V fragments direct from global (L2). Iter mt: compute S(mt+1)+exp into
// pt[1-cur] while PV(mt) reads pt[cur]; single barrier covers both.
// q pre-scaled by log2e in qkv -> exp is a bare v_exp_f32 (base-2).
__global__ __launch_bounds__(256) void attn_mfma(
    const __bf16* __restrict__ qth, const __bf16* __restrict__ qtl,
    const __bf16* __restrict__ kth, const __bf16* __restrict__ vb,
    __bf16* __restrict__ Opart, float* __restrict__ dpart)
{
    __shared__ __align__(16) __bf16 pt_s[2][64][72];   // 18432 B
    __shared__ float dbuf[4][36];

    const int t    = threadIdx.x;
    const int b    = blockIdx.z;
    const int ksp  = blockIdx.y;
    const int n0   = blockIdx.x * 64;
    const int w    = t >> 6;
    const int lane = t & 63;
    const int l31  = lane & 31;
    const int h    = lane >> 5;
    const int sr   = w & 1, sc = w >> 1;
    const int mbase = ksp * (NPIX / 2);

    const size_t qrow = ((size_t)b * NPIX + n0 + 32 * sr + l31) * QKC;
    bf16x8 qh0 = *(const bf16x8*)(qth + qrow + 8 * h);
    bf16x8 qh1 = *(const bf16x8*)(qth + qrow + 16 + 8 * h);
    bf16x8 ql0 = *(const bf16x8*)(qtl + qrow + 8 * h);
    bf16x8 ql1 = *(const bf16x8*)(qtl + qrow + 16 + 8 * h);

    const __bf16* kbase  = kth + ((size_t)b * NPIX + mbase + 32 * sc + l31) * QKC + 8 * h;
    const __bf16* vbase0 = vb + ((size_t)(b * NI) + 64 * w + l31) * NPIX + mbase + 8 * h;
    const __bf16* vbase1 = vbase0 + (size_t)32 * NPIX;

    bf16x8 ones;
    #pragma unroll
    for (int i = 0; i < 8; ++i) ones[i] = (__bf16)1.0f;

    f32x16 a00 = zero16(), a01 = zero16(), a10 = zero16(), a11 = zero16();
    f32x16 d = zero16();

    const int NIT = NPIX / 2 / 64;

    // prologue: S(0) -> pt[0]; then prefetch K(1)
    bf16x8 kh0 = *(const bf16x8*)kbase;
    bf16x8 kh1 = *(const bf16x8*)(kbase + 16);
    {
        f32x16 s = zero16();
        s = __builtin_amdgcn_mfma_f32_32x32x16_bf16(qh0, kh0, s, 0, 0, 0);
        s = __builtin_amdgcn_mfma_f32_32x32x16_bf16(qh1, kh1, s, 0, 0, 0);
        s = __builtin_amdgcn_mfma_f32_32x32x16_bf16(ql0, kh0, s, 0, 0, 0);
        s = __builtin_amdgcn_mfma_f32_32x32x16_bf16(ql1, kh1, s, 0, 0, 0);
        #pragma unroll
        for (int r = 0; r < 16; ++r) {
            int rit = (r & 3) + 8 * (r >> 2) + 4 * h;
            pt_s[0][32 * sr + rit][32 * sc + l31] = (__bf16)__builtin_amdgcn_exp2f(s[r]);
        }
    }
    kh0 = *(const bf16x8*)(kbase + (size_t)64 * QKC);
    kh1 = *(const bf16x8*)(kbase + (size_t)64 * QKC + 16);
    __syncthreads();

    for (int mt = 0; mt < NIT; ++mt) {
        const int cur = mt & 1;

        bf16x8 vf0[4], vf1[4];
        #pragma unroll
        for (int ks = 0; ks < 4; ++ks) {
            vf0[ks] = *(const bf16x8*)(vbase0 + (size_t)mt * 64 + ks * 16);
            vf1[ks] = *(const bf16x8*)(vbase1 + (size_t)mt * 64 + ks * 16);
        }

        if (mt < NIT - 1) {   // S(mt+1) -> pt[1-cur], overlapped with PV below
            f32x16 s = zero16();
            s = __builtin_amdgcn_mfma_f32_32x32x16_bf16(qh0, kh0, s, 0, 0, 0);
            s = __builtin_amdgcn_mfma_f32_32x32x16_bf16(qh1, kh1, s, 0, 0, 0);
            s = __builtin_amdgcn_mfma_f32_32x32x16_bf16(ql0, kh0, s, 0, 0, 0);
            s = __builtin_amdgcn_mfma_f32_32x32x16_bf16(ql1, kh1, s, 0, 0, 0);
            if (mt < NIT - 2) {
                const __bf16* kp = kbase + (size_t)(mt + 2) * 64 * QKC;
                kh0 = *(const bf16x8*)kp;
                kh1 = *(const bf16x8*)(kp + 16);
            }
            #pragma unroll
            for (int r = 0; r < 16; ++r) {
                int rit = (r & 3) + 8 * (r >> 2) + 4 * h;
                pt_s[1 - cur][32 * sr + rit][32 * sc + l31] = (__bf16)__builtin_amdgcn_exp2f(s[r]);
            }
        }

        #pragma unroll
        for (int ks = 0; ks < 4; ++ks) {
            bf16x8 pa0 = *(const bf16x8*)&pt_s[cur][l31][ks * 16 + 8 * h];
            bf16x8 pa1 = *(const bf16x8*)&pt_s[cur][32 + l31][ks * 16 + 8 * h];
            if ((ks >> 1) == sc)
                d = __builtin_amdgcn_mfma_f32_32x32x16_bf16(sr ? pa1 : pa0, ones, d, 0, 0, 0);
            a00 = __builtin_amdgcn_mfma_f32_32x32x16_bf16(pa0, vf0[ks], a00, 0, 0, 0);
            a10 = __builtin_amdgcn_mfma_f32_32x32x16_bf16(pa1, vf0[ks], a10, 0, 0, 0);
            a01 = __builtin_amdgcn_mfma_f32_32x32x16_bf16(pa0, vf1[ks], a01, 0, 0, 0);
            a11 = __builtin_amdgcn_mfma_f32_32x32x16_bf16(pa1, vf1[ks], a11, 0, 0, 0);
        }
        __syncthreads();   // pt[1-cur] written by all; pt[cur] consumed by all
    }

    // ---- epilogue: d partials via LDS, direct Opart stores ----
    if (l31 == 0) {
        #pragma unroll
        for (int r = 0; r < 16; ++r) {
            int rit = (r & 3) + 8 * (r >> 2) + 4 * h;
            dbuf[w][rit] = d[r];
        }
    }
    __syncthreads();
    if (w < 2 && l31 == 0) {
        size_t dbase = ((size_t)(ksp * BS + b)) * NPIX + n0 + 32 * w;
        #pragma unroll
        for (int r = 0; r < 16; ++r) {
            int rit = (r & 3) + 8 * (r >> 2) + 4 * h;
            dpart[dbase + rit] = dbuf[w][rit] + dbuf[w + 2][rit];
        }
    }

    size_t obase = (((size_t)(ksp * BS + b)) * NI + 64 * w + l31) * NPIX + n0;
    #pragma unroll
    for (int rq = 0; rq < 4; ++rq) {
        int nn = 8 * rq + 4 * h;
        __align__(8) __bf16 t00[4], t10[4], t01[4], t11[4];
        #pragma unroll
        for (int i = 0; i < 4; ++i) {
            t00[i] = (__bf16)a00[4 * rq + i];
            t10[i] = (__bf16)a10[4 * rq + i];
            t01[i] = (__bf16)a01[4 * rq + i];
            t11[i] = (__bf16)a11[4 * rq + i];
        }
        *(uint2*)(Opart + obase + nn)                          = *(const uint2*)t00;
        *(uint2*)(Opart + obase + 32 + nn)                     = *(const uint2*)t10;
        *(uint2*)(Opart + obase + (size_t)32 * NPIX + nn)      = *(const uint2*)t01;
        *(uint2*)(Opart + obase + (size_t)32 * NPIX + 32 + nn) = *(const uint2*)t11;
    }
}

// ---------------- Kernel 3: combine ----------------
__global__ __launch_bounds__(256) void combine(
    const float* __restrict__ x, const float* __restrict__ gamma,
    const __bf16* __restrict__ Opart, const float* __restrict__ dpart,
    float* __restrict__ out)
{
    int idx = (blockIdx.x * 256 + threadIdx.x) * 4;
    int n = idx & (NPIX - 1);
    int c = (idx >> 12) & (NI - 1);
    int b = idx >> 20;

    size_t o0 = (((size_t)(0 * BS + b)) * NI + c) * NPIX + n;
    size_t o1 = (((size_t)(1 * BS + b)) * NI + c) * NPIX + n;
    bf16x4 p0 = *(const bf16x4*)(Opart + o0);
    bf16x4 p1 = *(const bf16x4*)(Opart + o1);
    float4 da = *(const float4*)(dpart + ((size_t)(0 * BS + b)) * NPIX + n);
    float4 db = *(const float4*)(dpart + ((size_t)(1 * BS + b)) * NPIX + n);
    size_t xb = ((size_t)(b * NI) + c) * NPIX + n;
    float4 xv = *(const float4*)(x + xb);
    float g = gamma[c];

    float4 r;
    r.x = g * (((float)p0[0] + (float)p1[0]) / (da.x + db.x)) + xv.x;
    r.y = g * (((float)p0[1] + (float)p1[1]) / (da.y + db.y)) + xv.y;
    r.z = g * (((float)p0[2] + (float)p1[2]) / (da.z + db.z)) + xv.z;
    r.w = g * (((float)p0[3] + (float)p1[3]) / (da.w + db.w)) + xv.w;
    *(float4*)(out + xb) = r;
}

extern "C" void kernel_launch(void* const* d_in, const int* in_sizes, int n_in,
                              void* d_out, int out_size, void* d_ws, size_t ws_size,
                              hipStream_t stream)
{
    const float* x     = (const float*)d_in[0];
    const float* wq    = (const float*)d_in[1];
    const float* bq    = (const float*)d_in[2];
    const float* wk    = (const float*)d_in[3];
    const float* bk    = (const float*)d_in[4];
    const float* wv    = (const float*)d_in[5];
    const float* bv    = (const float*)d_in[6];
    const float* gamma = (const float*)d_in[7];
    float* out = (float*)d_out;

    const size_t WSZ = (size_t)320 * NI;
    const size_t QSZ = (size_t)BS * NPIX * QKC;
    const size_t VSZ = (size_t)BS * NI * NPIX;
    __bf16* wbf   = (__bf16*)d_ws;
    __bf16* qth   = wbf + WSZ;
    __bf16* qtl   = qth + QSZ;
    __bf16* kth   = qtl + QSZ;
    __bf16* vb    = kth + QSZ;
    __bf16* Opart = vb + VSZ;
    float*  dpart = (float*)(Opart + 2 * VSZ);

    wconv<<<dim3(80), 256, 0, stream>>>(wq, wk, wv, wbf);
    qkv_mfma<<<dim3(NPIX / 32, BS), 256, 0, stream>>>(x, wbf, bq, bk, bv,
                                                      qth, qtl, kth, vb);
    attn_mfma<<<dim3(64, 2, BS), 256, 0, stream>>>(qth, qtl, kth, vb, Opart, dpart);
    combine<<<dim3(BS * NI * NPIX / 1024), 256, 0, stream>>>(x, gamma, Opart, dpart, out);
}